// Round 8
// baseline (314.150 us; speedup 1.0000x reference)
//
#include <hip/hip_runtime.h>
#include <math.h>

// Problem constants
#define B_ 8
#define C_ 256
#define H_ 56
#define W_ 56
#define N_ 3136  // 56*56 = 49*64
#define BN_ (B_*N_)
#define LOG2E 1.44269504088896340736f

typedef __attribute__((ext_vector_type(8))) short short8;
typedef __attribute__((ext_vector_type(4))) float f32x4;
typedef __attribute__((ext_vector_type(16))) float f32x16;
typedef __attribute__((ext_vector_type(4))) unsigned short u16x4;
#define MFMA16(A, Bf, Cf) __builtin_amdgcn_mfma_f32_16x16x32_bf16((A), (Bf), (Cf), 0, 0, 0)
#define MFMA32(A, Bf, Cf) __builtin_amdgcn_mfma_f32_32x32x16_bf16((A), (Bf), (Cf), 0, 0, 0)

// -------------------- workspace layout (ushort units) --------------------
#define XT_ELEMS (B_*58*64*256)           // 7,602,176
#define A_ELEMS  (320*2304)               // 737,280
#define AHI_OFF  (2*XT_ELEMS)
#define ALO_OFF  (AHI_OFF + A_ELEMS)
#define QKT_HI_OFF (ALO_OFF + A_ELEMS)
#define QKT_ELEMS  (B_*N_*64)             // 1,605,632 = QF_ELEMS + KF_ELEMS
#define QKT_LO_OFF (QKT_HI_OFF + QKT_ELEMS)
#define VBF_OFF    (QKT_LO_OFF + QKT_ELEMS)
#define VBF_ELEMS  (B_*C_*N_)             // 6,422,528

// Fragment-order layouts: attn lane L reads base + L*16B.
// Qf: [b][q16 (pix>>4, 196)][fq*16 + ln (64)][8]   (features 0..31, PRE-SCALED by log2e)
// Kf: [b][jt (49)][tj (4)][fq*16 + ln (64)][8]     (features 32..63)
// Vf: [b][cg (8)][jt (49)][s (4)][hh*32 + c31 (64)][8]
#define QF_ELEMS (B_*196*64*8)            // 802,816

// Af fragment-order weights: [rowgrp 20][s 9][cc 8][L 64][8]

// LDS swizzle for conv B-slabs ((col>>2) term -> 2-way ds_read aliasing = free)
#define SX(col) ((((col) & 3)) ^ (((col) >> 2) & 3))
#define SWZ(r, col, c8) ((((r)*64 + (col))*4) + ((c8) ^ SX(col)))

// P LDS row stride (ushorts) for attn
#define PSTR 76
// Vs (conv v-epilogue LDS transpose) pixel stride
#define VSTR 58

__device__ inline unsigned short f2bf(float f) {
    unsigned u = __float_as_uint(f);
    unsigned r = (u + 0x7fffu + ((u >> 16) & 1u)) >> 16;   // RNE
    return (unsigned short)r;
}
__device__ inline float bf2f(unsigned short h) {
    return __uint_as_float(((unsigned)h) << 16);
}
__device__ inline float exp2_hw(float x) {
    float r; asm("v_exp_f32 %0, %1" : "=v"(r) : "v"(x)); return r;
}
__device__ inline unsigned cvt_pk_bf16(float lo, float hi) {
    unsigned r; asm("v_cvt_pk_bf16_f32 %0, %1, %2" : "=v"(r) : "v"(lo), "v"(hi)); return r;
}
// direct global->LDS DMA, 16B/lane; LDS dest = (wave-uniform base) + lane*16
__device__ inline void gl_lds16(const unsigned short* g, uint4* l) {
    __builtin_amdgcn_global_load_lds(
        (const __attribute__((address_space(1))) unsigned int*)g,
        (__attribute__((address_space(3))) unsigned int*)l,
        16, 0, 0);
}

// ---------------------------------------------------------------------------
// Kernel 0: zero ONLY the pad rows/cols.
// ---------------------------------------------------------------------------
__global__ __launch_bounds__(256) void zero_pads(
    unsigned short* __restrict__ xhi, unsigned short* __restrict__ xlo)
{
    const int g = blockIdx.x*256 + threadIdx.x;   // uint4 units, 2*61440 total
    const int half = 61440;
    unsigned short* base = (g < half) ? xhi : xlo;
    const int i = (g < half) ? g : g - half;
    const int b = i / 7680, rem = i - b*7680;
    const int slot = rem >> 5, c8 = rem & 31;
    int row, col;
    if (slot < 64)       { row = 0;  col = slot; }
    else if (slot < 128) { row = 57; col = slot - 64; }
    else if (slot < 184) { row = slot - 127; col = 0; }   // rows 1..56
    else                 { row = slot - 183; col = 57; }  // rows 1..56
    const size_t o = ((size_t)((b*58 + row)*64 + col))*256 + c8*8;
    *(uint4*)(base + o) = make_uint4(0, 0, 0, 0);
}

// ---------------------------------------------------------------------------
// Kernel 1a: x (fp32 NCHW) -> padded pixel-major bf16 hi/lo.
// ---------------------------------------------------------------------------
__global__ __launch_bounds__(256) void prep_x(
    const float* __restrict__ x,
    unsigned short* __restrict__ xhi, unsigned short* __restrict__ xlo)
{
    __shared__ float xs[64][57];
    const int cc = blockIdx.x, y = blockIdx.y, b = blockIdx.z;
    const int t = threadIdx.x;
    const int c0 = cc * 64;
    for (int idx = t; idx < 64 * 56; idx += 256) {
        const int ch = idx / 56, xc = idx - ch * 56;
        xs[ch][xc] = x[((size_t)(b*C_ + c0 + ch)*H_ + y)*W_ + xc];
    }
    __syncthreads();
    for (int idx = t; idx < 56 * 32; idx += 256) {
        const int xc = idx >> 5, chp = idx & 31;
        const float v0 = xs[2*chp][xc], v1 = xs[2*chp + 1][xc];
        const unsigned short h0 = f2bf(v0), h1 = f2bf(v1);
        const unsigned short l0 = f2bf(v0 - bf2f(h0));
        const unsigned short l1 = f2bf(v1 - bf2f(h1));
        const size_t o = ((size_t)(b*58 + y + 1) * 64 + (xc + 1)) * 256 + c0 + 2*chp;
        *(unsigned*)(xhi + o) = (unsigned)h0 | ((unsigned)h1 << 16);
        *(unsigned*)(xlo + o) = (unsigned)l0 | ((unsigned)l1 << 16);
    }
}

// ---------------------------------------------------------------------------
// Kernel 1b: weights -> Af_hi/Af_lo FRAGMENT order.
// ---------------------------------------------------------------------------
__global__ __launch_bounds__(256) void prep_w(
    const float* __restrict__ wq, const float* __restrict__ wk,
    const float* __restrict__ wv,
    unsigned short* __restrict__ Ahi, unsigned short* __restrict__ Alo)
{
    const int g = blockIdx.x * 256 + threadIdx.x;
    if (g >= 320 * 2304) return;
    const int m = g / 2304, k = g - m * 2304;
    const int s = k >> 8, c = k & 255;
    float w;
    if (m < 32)      w = wq[((size_t)m*C_ + c)*9 + s];
    else if (m < 64) w = wk[((size_t)(m-32)*C_ + c)*9 + s];
    else             w = wv[((size_t)(m-64)*C_ + c)*9 + s];
    const unsigned short h = f2bf(w);
    const int cc = (k >> 5) & 7, quad = (k >> 3) & 3, e = k & 7;
    const size_t o = ((((size_t)(m >> 4)*9 + s)*8 + cc)*64 + (quad*16 + (m & 15)))*8 + e;
    Ahi[o] = h;
    Alo[o] = f2bf(w - bf2f(h));
}

// ---------------------------------------------------------------------------
// Kernel 2: FUSED conv (R7 structure, unchanged). grid (b 8, y 56, z 2).
// ---------------------------------------------------------------------------
__global__ __launch_bounds__(256, 3) void conv_fused(
    const unsigned short* __restrict__ xhi, const unsigned short* __restrict__ xlo,
    const unsigned short* __restrict__ Ahi, const unsigned short* __restrict__ Alo,
    const float* __restrict__ bq, const float* __restrict__ bk,
    const float* __restrict__ bv,
    unsigned short* __restrict__ qkt_hi, unsigned short* __restrict__ qkt_lo,
    unsigned short* __restrict__ vbf)
{
    __shared__ uint4 SMEM[3080];   // 49.3 KB -> 3 blocks/CU
    const int b = blockIdx.x, y = blockIdx.y, z = blockIdx.z;
    const int t = threadIdx.x;
    const int w = t >> 6, L = t & 63;
    const int ln = L & 15, quad = L >> 4;

    size_t gofs[3];
#pragma unroll
    for (int i = 0; i < 3; i++) {
        const int ci = w*192 + i*64 + L;
        const int r = ci >> 8, col = (ci >> 2) & 63;
        const int c8 = (ci & 3) ^ SX(col);
        gofs[i] = ((size_t)((b*58 + y + r)*64 + col))*256 + c8*8;
    }

    if (z == 0) {
        // ---------------- q/k path: 2 rowgrp x 2 pxtile per wave ----------
        const int wrg = w >> 1, wnt = w & 1;
        f32x4 acc[2][2];
#pragma unroll
        for (int i = 0; i < 2; i++) { acc[i][0] = (f32x4)0.0f; acc[i][1] = (f32x4)0.0f; }

#pragma unroll
        for (int i = 0; i < 3; i++) {
            gl_lds16(xhi + gofs[i], SMEM + w*192 + i*64);
            gl_lds16(xlo + gofs[i], SMEM + 768 + w*192 + i*64);
        }
        __syncthreads();

        for (int cc = 0; cc < 8; cc++) {
            const int buf = cc & 1;
            const uint4* sH = SMEM + buf*1536;
            const uint4* sL = sH + 768;
            if (cc < 7) {
                uint4* nB = SMEM + (buf^1)*1536;
#pragma unroll
                for (int i = 0; i < 3; i++) {
                    gl_lds16(xhi + gofs[i] + (cc+1)*32, nB + w*192 + i*64);
                    gl_lds16(xlo + gofs[i] + (cc+1)*32, nB + 768 + w*192 + i*64);
                }
            }
#pragma unroll
            for (int s = 0; s < 9; s++) {
                const int dx = s % 3 - 1;
                const int r = s / 3;
                short8 ah[2], al[2];
#pragma unroll
                for (int rgi = 0; rgi < 2; rgi++) {
                    const int rg = wrg*2 + rgi;
                    const size_t aoff = (((size_t)(rg*9 + s)*8 + cc)*64 + L)*8;
                    ah[rgi] = *(const short8*)(Ahi + aoff);
                    al[rgi] = *(const short8*)(Alo + aoff);
                }
#pragma unroll
                for (int nti = 0; nti < 2; nti++) {
                    const int col = (wnt*2 + nti)*16 + ln + dx + 1;
                    const int i4 = SWZ(r, col, quad);
                    const short8 bh = *(const short8*)&sH[i4];
                    const short8 bl = *(const short8*)&sL[i4];
#pragma unroll
                    for (int rgi = 0; rgi < 2; rgi++) {
                        acc[rgi][nti] = MFMA16(ah[rgi], bh, acc[rgi][nti]);
                        acc[rgi][nti] = MFMA16(ah[rgi], bl, acc[rgi][nti]);
                        acc[rgi][nti] = MFMA16(al[rgi], bh, acc[rgi][nti]);
                    }
                }
            }
            if (cc < 7) __syncthreads();
        }

        // epilogue: fragment-order Qf/Kf writes; Q pre-scaled by log2e
#pragma unroll
        for (int rgi = 0; rgi < 2; rgi++) {
            const int rg = wrg*2 + rgi;
            const int m0 = rg*16 + quad*4;
#pragma unroll
            for (int nti = 0; nti < 2; nti++) {
                const int px = (wnt*2 + nti)*16 + ln;
                if (px >= 56) continue;
                const int pix = y*56 + px;
                u16x4 hi4, lo4;
#pragma unroll
                for (int r = 0; r < 4; r++) {
                    const int m = m0 + r;
                    const float bias = (m < 32) ? bq[m] : bk[m - 32];
                    float val = acc[rgi][nti][r] + bias;
                    if (rg < 2) val *= LOG2E;
                    const unsigned short h = f2bf(val);
                    hi4[r] = h;
                    lo4[r] = f2bf(val - bf2f(h));
                }
                size_t o;
                if (rg < 2) {
                    o = ((size_t)(b*196 + (pix >> 4))*64 + (m0 >> 3)*16 + (pix & 15))*8 + (m0 & 7);
                } else {
                    const int mk0 = m0 - 32;
                    o = (size_t)QF_ELEMS +
                        (((size_t)(b*49 + (pix >> 6))*4 + ((pix >> 4) & 3))*64
                         + (mk0 >> 3)*16 + (pix & 15))*8 + (mk0 & 7);
                }
                *(u16x4*)(qkt_hi + o) = hi4;
                *(u16x4*)(qkt_lo + o) = lo4;
            }
        }
    } else {
        // ------- v path: all 256 channels, 4 rowgroups per wave -------
        f32x4 acc[4][4];
#pragma unroll
        for (int rg = 0; rg < 4; rg++)
#pragma unroll
            for (int nt = 0; nt < 4; nt++) acc[rg][nt] = (f32x4)0.0f;

#pragma unroll
        for (int i = 0; i < 3; i++)
            gl_lds16(xhi + gofs[i], SMEM + w*192 + i*64);
        __syncthreads();

        for (int cc = 0; cc < 8; cc++) {
            const int buf = cc & 1;
            const uint4* sH = SMEM + buf*768;
            if (cc < 7) {
                uint4* nB = SMEM + (buf^1)*768;
#pragma unroll
                for (int i = 0; i < 3; i++)
                    gl_lds16(xhi + gofs[i] + (cc+1)*32, nB + w*192 + i*64);
            }
#pragma unroll
            for (int s = 0; s < 9; s++) {
                const int dx = s % 3 - 1;
                const int r = s / 3;
                short8 a[4];
#pragma unroll
                for (int rg = 0; rg < 4; rg++) {
                    const size_t aoff = (((size_t)((4 + w*4 + rg)*9 + s)*8 + cc)*64 + L)*8;
                    a[rg] = *(const short8*)(Ahi + aoff);
                }
#pragma unroll
                for (int nt = 0; nt < 4; nt++) {
                    const int col = nt*16 + ln + dx + 1;
                    const short8 bf = *(const short8*)&sH[SWZ(r, col, quad)];
#pragma unroll
                    for (int rg = 0; rg < 4; rg++)
                        acc[rg][nt] = MFMA16(a[rg], bf, acc[rg][nt]);
                }
            }
            __syncthreads();
        }

        // ---- epilogue: LDS transpose (256ch x 56px) -> dense Vf tiles ----
        unsigned short* Vs = (unsigned short*)SMEM;   // [256][VSTR]
#pragma unroll
        for (int rg = 0; rg < 4; rg++)
#pragma unroll
            for (int nt = 0; nt < 4; nt++) {
                const int px = nt*16 + ln;
                if (px >= 56) continue;
#pragma unroll
                for (int r = 0; r < 4; r++) {
                    const int cl = (w*4 + rg)*16 + quad*4 + r;
                    Vs[cl*VSTR + px] = f2bf(acc[rg][nt][r] + bv[cl]);
                }
            }
        __syncthreads();
        const int p0 = y*56;
        const int hh = L >> 5, c31 = L & 31;
        const int gend = (p0 + 55) >> 4;
        for (int gi = p0 >> 4; gi <= gend; gi++) {
            const int pxl0 = gi*16 + hh*8 - p0;
            if (pxl0 >= 0 && pxl0 + 8 <= 56) {
#pragma unroll
                for (int cgk = 0; cgk < 2; cgk++) {
                    const int cg = w*2 + cgk;
                    const short8 vv = *(const short8*)&Vs[(cg*32 + c31)*VSTR + pxl0];
                    const size_t o = ((((size_t)(b*8 + cg)*49 + (gi >> 2))*4 + (gi & 3))*64 + L)*8;
                    *(short8*)(vbf + o) = vv;
                }
            }
        }
    }
}

// ---------------------------------------------------------------------------
// Kernel 3: fused flash attention, R8: 4-wave blocks, chalf MERGED.
// grid (98*8, jh 2) = 1568 blocks, block 256 = 4 waves.
// Waves 0-1: S^T + softmax for the 32 i-rows (ONCE — previously duplicated
// across two chalf blocks); publish P + alpha in LDS. All 4 waves: PV, each
// owning 64 channels (4x64 = 256). Removes half the S-MFMA, half the softmax
// VALU, half the K/Q fetch, half the P writes from an issue-bound kernel.
// ---------------------------------------------------------------------------
__global__ __launch_bounds__(256, 4) void attn_flash4w(
    const unsigned short* __restrict__ qkt_hi, const unsigned short* __restrict__ qkt_lo,
    const unsigned short* __restrict__ vbf,
    unsigned short* __restrict__ op0, unsigned short* __restrict__ op1,
    float* __restrict__ mlbase)
{
    __shared__ unsigned short P[2][32*PSTR];   // 9.5 KB
    __shared__ float alphaL[2][32];

    const int bx = blockIdx.x;
    const int b = bx & 7, it = bx >> 3;
    const int jh = blockIdx.y;
    const int jt0 = jh * 25, njt = 25 - jh;    // 25 / 24 tiles
    const int i_base = it * 32;
    const int t = threadIdx.x;
    const int w = t >> 6, L = t & 63;
    const int ln = L & 15, quad = L >> 4;
    const int l32 = L & 31, h32 = L >> 5;

    const unsigned short* Kf_hi = qkt_hi + QF_ELEMS;
    const unsigned short* Kf_lo = qkt_lo + QF_ELEMS;

    // Q fragments: only waves 0-1 (S-producer waves)
    short8 qh = (short8)0, ql = (short8)0;
    if (w < 2) {
        const size_t qoff = ((size_t)(b*196 + it*2 + w)*64 + L)*8;
        qh = *(const short8*)(qkt_hi + qoff);
        ql = *(const short8*)(qkt_lo + qoff);
    }

    float m_run = -INFINITY, l_run = 0.0f;
    f32x16 O0 = (f32x16)0.0f, O1 = (f32x16)0.0f;
    // each wave owns channel-groups 2w, 2w+1 (64 channels)
    const unsigned short* vt0 = vbf + ((size_t)(b*8 + w*2)*49)*2048 + (size_t)L*8;
    const unsigned short* vt1 = vt0 + (size_t)49*2048;
    const unsigned short* kbh = Kf_hi + (size_t)b*49*2048 + (size_t)L*8;
    const unsigned short* kbl = Kf_lo + (size_t)b*49*2048 + (size_t)L*8;

    for (int jtl = 0; jtl < njt; jtl++) {
        const int jt = jt0 + jtl;
        const int buf = jtl & 1;

        // ---- V prefetch (all waves; hidden under S-phase / barrier wait) ----
        short8 Va[4], Vb[4];
#pragma unroll
        for (int s = 0; s < 4; s++) {
            Va[s] = *(const short8*)(vt0 + jt*2048 + s*512);
            Vb[s] = *(const short8*)(vt1 + jt*2048 + s*512);
        }

        if (w < 2) {
            // ---- S^T phase (waves 0-1 only; computed ONCE per tile) ----
            f32x4 sacc[4];
#pragma unroll
            for (int tj = 0; tj < 4; tj++) {
                const short8 kh = *(const short8*)(kbh + jt*2048 + tj*512);
                const short8 kl = *(const short8*)(kbl + jt*2048 + tj*512);
                f32x4 a = (f32x4)0.0f;
                a = MFMA16(kh, qh, a);
                a = MFMA16(kh, ql, a);
                a = MFMA16(kl, qh, a);
                sacc[tj] = a;
            }
            float mt0 = fmaxf(fmaxf(sacc[0][0], sacc[0][1]), fmaxf(sacc[0][2], sacc[0][3]));
            float mt1 = fmaxf(fmaxf(sacc[1][0], sacc[1][1]), fmaxf(sacc[1][2], sacc[1][3]));
            float mt2 = fmaxf(fmaxf(sacc[2][0], sacc[2][1]), fmaxf(sacc[2][2], sacc[2][3]));
            float mt3 = fmaxf(fmaxf(sacc[3][0], sacc[3][1]), fmaxf(sacc[3][2], sacc[3][3]));
            float mx = fmaxf(fmaxf(mt0, mt1), fmaxf(mt2, mt3));
            mx = fmaxf(mx, __shfl_xor(mx, 16));
            mx = fmaxf(mx, __shfl_xor(mx, 32));

            float alpha = 1.0f;
            if (__any(mx > m_run + 8.0f)) {      // defer-max (T13)
                const float m_new = fmaxf(m_run, mx);
                alpha = exp2_hw(m_run - m_new);
                m_run = m_new;
            }

#pragma unroll
            for (int tj = 0; tj < 4; tj++)
#pragma unroll
                for (int r = 0; r < 4; r++)
                    sacc[tj][r] = exp2_hw(sacc[tj][r] - m_run);
            float s0 = (sacc[0][0] + sacc[0][1]) + (sacc[0][2] + sacc[0][3]);
            float s1 = (sacc[1][0] + sacc[1][1]) + (sacc[1][2] + sacc[1][3]);
            float s2 = (sacc[2][0] + sacc[2][1]) + (sacc[2][2] + sacc[2][3]);
            float s3 = (sacc[3][0] + sacc[3][1]) + (sacc[3][2] + sacc[3][3]);
            float ps = (s0 + s1) + (s2 + s3);
            ps += __shfl_xor(ps, 16);
            ps += __shfl_xor(ps, 32);
            l_run = l_run * alpha + ps;

            unsigned short* prow = &P[buf][(w*16 + ln)*PSTR];
#pragma unroll
            for (int tj = 0; tj < 4; tj++) {
                uint2 pp;
                pp.x = cvt_pk_bf16(sacc[tj][0], sacc[tj][1]);
                pp.y = cvt_pk_bf16(sacc[tj][2], sacc[tj][3]);
                *(uint2*)(prow + tj*16 + quad*4) = pp;
            }
            if (quad == 0) alphaL[buf][w*16 + ln] = alpha;
        }

        __syncthreads();   // P[buf] + alphaL[buf] ready for all 4 waves

        // ---- PV phase: all 4 waves, 64 channels each ----
        const float a = alphaL[buf][l32];
        if (__any(a != 1.0f)) {
#pragma unroll
            for (int rg = 0; rg < 16; rg++) { O0[rg] *= a; O1[rg] *= a; }
        }
        short8 Bp[4];
#pragma unroll
        for (int s = 0; s < 4; s++) {
            Bp[s] = *(const short8*)&P[buf][l32*PSTR + s*16 + h32*8];
            O0 = MFMA32(Va[s], Bp[s], O0);
        }
#pragma unroll
        for (int s = 0; s < 4; s++)
            O1 = MFMA32(Vb[s], Bp[s], O1);
    }

    // ---- epilogue ----
    if (w < 2 && quad == 0) {
        const int i = i_base + w*16 + ln;
        mlbase[jh*BN_ + b*N_ + i]       = m_run;
        mlbase[(2 + jh)*BN_ + b*N_ + i] = l_run;
    }
    unsigned short* OP = jh ? op1 : op0;
    const int pix = i_base + l32;
#pragma unroll
    for (int g = 0; g < 2; g++) {
        const f32x16 Ot = g ? O1 : O0;
        const int cg = w*64 + g*32;
#pragma unroll
        for (int reg = 0; reg < 16; reg++) {
            const int c = cg + (reg & 3) + 8*(reg >> 2) + 4*h32;
            OP[(size_t)(b*C_ + c)*N_ + pix] = f2bf(Ot[reg]);
        }
    }
}

// ---------------------------------------------------------------------------
// Kernel 3b: per-pixel combine coefficients (exp2 domain, gamma folded).
// ---------------------------------------------------------------------------
__global__ __launch_bounds__(256) void coef_pre(
    const float* __restrict__ mlbase, const float* __restrict__ gptr,
    float* __restrict__ coef)
{
    const int i = blockIdx.x*256 + threadIdx.x;   // 0..BN-1
    const float m0 = mlbase[i],        m1 = mlbase[BN_ + i];
    const float l0 = mlbase[2*BN_ + i], l1 = mlbase[3*BN_ + i];
    const float mm = fmaxf(m0, m1);
    const float a0 = exp2_hw(m0 - mm), a1 = exp2_hw(m1 - mm);
    const float inv = gptr[0] / (a0*l0 + a1*l1);
    coef[2*i]   = a0 * inv;
    coef[2*i+1] = a1 * inv;
}

// ---------------------------------------------------------------------------
// Kernel 4: combine, vectorized: 4 px/thread, ushort4/float4.
// ---------------------------------------------------------------------------
__global__ __launch_bounds__(256) void combine(
    const unsigned short* __restrict__ op0, const unsigned short* __restrict__ op1,
    const float* __restrict__ coef,
    const float* __restrict__ x, float* __restrict__ out)
{
    const int bc = blockIdx.x;
    const int b = bc >> 8;
    const size_t base = (size_t)bc * N_;
    const float2* cf = (const float2*)coef + (size_t)b * N_;
    for (int pq = threadIdx.x; pq < 784; pq += 256) {
        const int p0 = pq * 4;
        const ushort4 o0 = *(const ushort4*)(op0 + base + p0);
        const ushort4 o1 = *(const ushort4*)(op1 + base + p0);
        const float4 xx = *(const float4*)(x + base + p0);
        float4 r;
        { const float2 c = cf[p0 + 0]; r.x = xx.x + c.x*bf2f(o0.x) + c.y*bf2f(o1.x); }
        { const float2 c = cf[p0 + 1]; r.y = xx.y + c.x*bf2f(o0.y) + c.y*bf2f(o1.y); }
        { const float2 c = cf[p0 + 2]; r.z = xx.z + c.x*bf2f(o0.z) + c.y*bf2f(o1.z); }
        { const float2 c = cf[p0 + 3]; r.w = xx.w + c.x*bf2f(o0.w) + c.y*bf2f(o1.w); }
        *(float4*)(out + base + p0) = r;
    }
}

// ---------------------------------------------------------------------------
extern "C" void kernel_launch(void* const* d_in, const int* in_sizes, int n_in,
                              void* d_out, int out_size, void* d_ws, size_t ws_size,
                              hipStream_t stream)
{
    (void)in_sizes; (void)n_in; (void)out_size; (void)ws_size;
    const float* x  = (const float*)d_in[0];
    const float* wq = (const float*)d_in[1];
    const float* bq = (const float*)d_in[2];
    const float* wk = (const float*)d_in[3];
    const float* bk = (const float*)d_in[4];
    const float* wv = (const float*)d_in[5];
    const float* bv = (const float*)d_in[6];
    const float* gm = (const float*)d_in[7];
    float* out = (float*)d_out;

    unsigned short* u = (unsigned short*)d_ws;
    unsigned short* xhi = u;                      // conv input; later O-partial jh=0
    unsigned short* xlo = u + XT_ELEMS;           // conv input; later O-partial jh=1
    unsigned short* Ahi = u + AHI_OFF;            // Af weights; later m/l
    unsigned short* Alo = u + ALO_OFF;            // Af lo; later coef table
    unsigned short* qkt_hi = u + QKT_HI_OFF;      // [Qf_hi | Kf_hi]
    unsigned short* qkt_lo = u + QKT_LO_OFF;      // [Qf_lo | Kf_lo]
    unsigned short* vbf = u + VBF_OFF;            // Vf fragment-order
    float* mlbase = (float*)Ahi;                  // 4 * B*N floats
    float* coef = (float*)Alo;                    // 2 * B*N floats

    hipLaunchKernelGGL(zero_pads, dim3(480), dim3(256), 0, stream, xhi, xlo);
    hipLaunchKernelGGL(prep_x, dim3(4, 56, 8), dim3(256), 0, stream, x, xhi, xlo);
    hipLaunchKernelGGL(prep_w, dim3(2880), dim3(256), 0, stream, wq, wk, wv, Ahi, Alo);
    hipLaunchKernelGGL(conv_fused, dim3(8, 56, 2), dim3(256), 0, stream,
                       xhi, xlo, Ahi, Alo, bq, bk, bv, qkt_hi, qkt_lo, vbf);
    hipLaunchKernelGGL(attn_flash4w, dim3(98*8, 2), dim3(256), 0, stream,
                       qkt_hi, qkt_lo, vbf, xhi, xlo, mlbase);
    hipLaunchKernelGGL(coef_pre, dim3(98), dim3(256), 0, stream, mlbase, gm, coef);
    hipLaunchKernelGGL(combine, dim3(2048), dim3(256), 0, stream,
                       xhi, xlo, coef, x, out);
}

// Round 9
// 295.456 us; speedup vs baseline: 1.0633x; 1.0633x over previous
//
#include <hip/hip_runtime.h>
#include <math.h>

// Problem constants
#define B_ 8
#define C_ 256
#define H_ 56
#define W_ 56
#define N_ 3136  // 56*56 = 49*64
#define BN_ (B_*N_)
#define LOG2E 1.44269504088896340736f

typedef __attribute__((ext_vector_type(8))) short short8;
typedef __attribute__((ext_vector_type(4))) float f32x4;
typedef __attribute__((ext_vector_type(16))) float f32x16;
typedef __attribute__((ext_vector_type(4))) unsigned short u16x4;
#define MFMA16(A, Bf, Cf) __builtin_amdgcn_mfma_f32_16x16x32_bf16((A), (Bf), (Cf), 0, 0, 0)
#define MFMA32(A, Bf, Cf) __builtin_amdgcn_mfma_f32_32x32x16_bf16((A), (Bf), (Cf), 0, 0, 0)

// -------------------- workspace layout (ushort units) --------------------
#define XT_ELEMS (B_*58*64*256)           // 7,602,176
#define A_ELEMS  (320*2304)               // 737,280
#define AHI_OFF  (2*XT_ELEMS)
#define ALO_OFF  (AHI_OFF + A_ELEMS)
#define QKT_HI_OFF (ALO_OFF + A_ELEMS)
#define QKT_ELEMS  (B_*N_*64)             // 1,605,632 = QF_ELEMS + KF_ELEMS
#define QKT_LO_OFF (QKT_HI_OFF + QKT_ELEMS)
#define VBF_OFF    (QKT_LO_OFF + QKT_ELEMS)
#define VBF_ELEMS  (B_*C_*N_)             // 6,422,528

// Fragment-order layouts: attn lane L reads base + L*16B.
// Qf: [b][q16 (pix>>4, 196)][fq*16 + ln (64)][8]   (features 0..31, PRE-SCALED by log2e)
// Kf: [b][jt (49)][tj (4)][fq*16 + ln (64)][8]     (features 32..63)
// Vf: [b][cg (8)][jt (49)][s (4)][hh*32 + c31 (64)][8]
#define QF_ELEMS (B_*196*64*8)            // 802,816

// Af fragment-order weights: [rowgrp 20][s 9][cc 8][L 64][8]

// LDS swizzle for conv B-slabs ((col>>2) term -> 2-way ds_read aliasing = free)
#define SX(col) ((((col) & 3)) ^ (((col) >> 2) & 3))
#define SWZ(r, col, c8) ((((r)*64 + (col))*4) + ((c8) ^ SX(col)))

// P LDS row stride (ushorts) for attn
#define PSTR 76
// Vs (conv v-epilogue LDS transpose) pixel stride
#define VSTR 58

__device__ inline unsigned short f2bf(float f) {
    unsigned u = __float_as_uint(f);
    unsigned r = (u + 0x7fffu + ((u >> 16) & 1u)) >> 16;   // RNE
    return (unsigned short)r;
}
__device__ inline float bf2f(unsigned short h) {
    return __uint_as_float(((unsigned)h) << 16);
}
__device__ inline float exp2_hw(float x) {
    float r; asm("v_exp_f32 %0, %1" : "=v"(r) : "v"(x)); return r;
}
__device__ inline unsigned cvt_pk_bf16(float lo, float hi) {
    unsigned r; asm("v_cvt_pk_bf16_f32 %0, %1, %2" : "=v"(r) : "v"(lo), "v"(hi)); return r;
}
// direct global->LDS DMA, 16B/lane; LDS dest = (wave-uniform base) + lane*16
__device__ inline void gl_lds16(const unsigned short* g, uint4* l) {
    __builtin_amdgcn_global_load_lds(
        (const __attribute__((address_space(1))) unsigned int*)g,
        (__attribute__((address_space(3))) unsigned int*)l,
        16, 0, 0);
}

// ---------------------------------------------------------------------------
// Kernel 0: zero ONLY the pad rows/cols.
// ---------------------------------------------------------------------------
__global__ __launch_bounds__(256) void zero_pads(
    unsigned short* __restrict__ xhi, unsigned short* __restrict__ xlo)
{
    const int g = blockIdx.x*256 + threadIdx.x;   // uint4 units, 2*61440 total
    const int half = 61440;
    unsigned short* base = (g < half) ? xhi : xlo;
    const int i = (g < half) ? g : g - half;
    const int b = i / 7680, rem = i - b*7680;
    const int slot = rem >> 5, c8 = rem & 31;
    int row, col;
    if (slot < 64)       { row = 0;  col = slot; }
    else if (slot < 128) { row = 57; col = slot - 64; }
    else if (slot < 184) { row = slot - 127; col = 0; }   // rows 1..56
    else                 { row = slot - 183; col = 57; }  // rows 1..56
    const size_t o = ((size_t)((b*58 + row)*64 + col))*256 + c8*8;
    *(uint4*)(base + o) = make_uint4(0, 0, 0, 0);
}

// ---------------------------------------------------------------------------
// Kernel 1a: x (fp32 NCHW) -> padded pixel-major bf16 hi/lo.
// ---------------------------------------------------------------------------
__global__ __launch_bounds__(256) void prep_x(
    const float* __restrict__ x,
    unsigned short* __restrict__ xhi, unsigned short* __restrict__ xlo)
{
    __shared__ float xs[64][57];
    const int cc = blockIdx.x, y = blockIdx.y, b = blockIdx.z;
    const int t = threadIdx.x;
    const int c0 = cc * 64;
    for (int idx = t; idx < 64 * 56; idx += 256) {
        const int ch = idx / 56, xc = idx - ch * 56;
        xs[ch][xc] = x[((size_t)(b*C_ + c0 + ch)*H_ + y)*W_ + xc];
    }
    __syncthreads();
    for (int idx = t; idx < 56 * 32; idx += 256) {
        const int xc = idx >> 5, chp = idx & 31;
        const float v0 = xs[2*chp][xc], v1 = xs[2*chp + 1][xc];
        const unsigned short h0 = f2bf(v0), h1 = f2bf(v1);
        const unsigned short l0 = f2bf(v0 - bf2f(h0));
        const unsigned short l1 = f2bf(v1 - bf2f(h1));
        const size_t o = ((size_t)(b*58 + y + 1) * 64 + (xc + 1)) * 256 + c0 + 2*chp;
        *(unsigned*)(xhi + o) = (unsigned)h0 | ((unsigned)h1 << 16);
        *(unsigned*)(xlo + o) = (unsigned)l0 | ((unsigned)l1 << 16);
    }
}

// ---------------------------------------------------------------------------
// Kernel 1b: weights -> Af_hi/Af_lo FRAGMENT order.
// ---------------------------------------------------------------------------
__global__ __launch_bounds__(256) void prep_w(
    const float* __restrict__ wq, const float* __restrict__ wk,
    const float* __restrict__ wv,
    unsigned short* __restrict__ Ahi, unsigned short* __restrict__ Alo)
{
    const int g = blockIdx.x * 256 + threadIdx.x;
    if (g >= 320 * 2304) return;
    const int m = g / 2304, k = g - m * 2304;
    const int s = k >> 8, c = k & 255;
    float w;
    if (m < 32)      w = wq[((size_t)m*C_ + c)*9 + s];
    else if (m < 64) w = wk[((size_t)(m-32)*C_ + c)*9 + s];
    else             w = wv[((size_t)(m-64)*C_ + c)*9 + s];
    const unsigned short h = f2bf(w);
    const int cc = (k >> 5) & 7, quad = (k >> 3) & 3, e = k & 7;
    const size_t o = ((((size_t)(m >> 4)*9 + s)*8 + cc)*64 + (quad*16 + (m & 15)))*8 + e;
    Ahi[o] = h;
    Alo[o] = f2bf(w - bf2f(h));
}

// ---------------------------------------------------------------------------
// Kernel 2: FUSED conv (R7 structure, unchanged). grid (b 8, y 56, z 2).
// ---------------------------------------------------------------------------
__global__ __launch_bounds__(256, 3) void conv_fused(
    const unsigned short* __restrict__ xhi, const unsigned short* __restrict__ xlo,
    const unsigned short* __restrict__ Ahi, const unsigned short* __restrict__ Alo,
    const float* __restrict__ bq, const float* __restrict__ bk,
    const float* __restrict__ bv,
    unsigned short* __restrict__ qkt_hi, unsigned short* __restrict__ qkt_lo,
    unsigned short* __restrict__ vbf)
{
    __shared__ uint4 SMEM[3080];   // 49.3 KB -> 3 blocks/CU
    const int b = blockIdx.x, y = blockIdx.y, z = blockIdx.z;
    const int t = threadIdx.x;
    const int w = t >> 6, L = t & 63;
    const int ln = L & 15, quad = L >> 4;

    size_t gofs[3];
#pragma unroll
    for (int i = 0; i < 3; i++) {
        const int ci = w*192 + i*64 + L;
        const int r = ci >> 8, col = (ci >> 2) & 63;
        const int c8 = (ci & 3) ^ SX(col);
        gofs[i] = ((size_t)((b*58 + y + r)*64 + col))*256 + c8*8;
    }

    if (z == 0) {
        // ---------------- q/k path: 2 rowgrp x 2 pxtile per wave ----------
        const int wrg = w >> 1, wnt = w & 1;
        f32x4 acc[2][2];
#pragma unroll
        for (int i = 0; i < 2; i++) { acc[i][0] = (f32x4)0.0f; acc[i][1] = (f32x4)0.0f; }

#pragma unroll
        for (int i = 0; i < 3; i++) {
            gl_lds16(xhi + gofs[i], SMEM + w*192 + i*64);
            gl_lds16(xlo + gofs[i], SMEM + 768 + w*192 + i*64);
        }
        __syncthreads();

        for (int cc = 0; cc < 8; cc++) {
            const int buf = cc & 1;
            const uint4* sH = SMEM + buf*1536;
            const uint4* sL = sH + 768;
            if (cc < 7) {
                uint4* nB = SMEM + (buf^1)*1536;
#pragma unroll
                for (int i = 0; i < 3; i++) {
                    gl_lds16(xhi + gofs[i] + (cc+1)*32, nB + w*192 + i*64);
                    gl_lds16(xlo + gofs[i] + (cc+1)*32, nB + 768 + w*192 + i*64);
                }
            }
#pragma unroll
            for (int s = 0; s < 9; s++) {
                const int dx = s % 3 - 1;
                const int r = s / 3;
                short8 ah[2], al[2];
#pragma unroll
                for (int rgi = 0; rgi < 2; rgi++) {
                    const int rg = wrg*2 + rgi;
                    const size_t aoff = (((size_t)(rg*9 + s)*8 + cc)*64 + L)*8;
                    ah[rgi] = *(const short8*)(Ahi + aoff);
                    al[rgi] = *(const short8*)(Alo + aoff);
                }
#pragma unroll
                for (int nti = 0; nti < 2; nti++) {
                    const int col = (wnt*2 + nti)*16 + ln + dx + 1;
                    const int i4 = SWZ(r, col, quad);
                    const short8 bh = *(const short8*)&sH[i4];
                    const short8 bl = *(const short8*)&sL[i4];
#pragma unroll
                    for (int rgi = 0; rgi < 2; rgi++) {
                        acc[rgi][nti] = MFMA16(ah[rgi], bh, acc[rgi][nti]);
                        acc[rgi][nti] = MFMA16(ah[rgi], bl, acc[rgi][nti]);
                        acc[rgi][nti] = MFMA16(al[rgi], bh, acc[rgi][nti]);
                    }
                }
            }
            if (cc < 7) __syncthreads();
        }

        // epilogue: fragment-order Qf/Kf writes; Q pre-scaled by log2e
#pragma unroll
        for (int rgi = 0; rgi < 2; rgi++) {
            const int rg = wrg*2 + rgi;
            const int m0 = rg*16 + quad*4;
#pragma unroll
            for (int nti = 0; nti < 2; nti++) {
                const int px = (wnt*2 + nti)*16 + ln;
                if (px >= 56) continue;
                const int pix = y*56 + px;
                u16x4 hi4, lo4;
#pragma unroll
                for (int r = 0; r < 4; r++) {
                    const int m = m0 + r;
                    const float bias = (m < 32) ? bq[m] : bk[m - 32];
                    float val = acc[rgi][nti][r] + bias;
                    if (rg < 2) val *= LOG2E;
                    const unsigned short h = f2bf(val);
                    hi4[r] = h;
                    lo4[r] = f2bf(val - bf2f(h));
                }
                size_t o;
                if (rg < 2) {
                    o = ((size_t)(b*196 + (pix >> 4))*64 + (m0 >> 3)*16 + (pix & 15))*8 + (m0 & 7);
                } else {
                    const int mk0 = m0 - 32;
                    o = (size_t)QF_ELEMS +
                        (((size_t)(b*49 + (pix >> 6))*4 + ((pix >> 4) & 3))*64
                         + (mk0 >> 3)*16 + (pix & 15))*8 + (mk0 & 7);
                }
                *(u16x4*)(qkt_hi + o) = hi4;
                *(u16x4*)(qkt_lo + o) = lo4;
            }
        }
    } else {
        // ------- v path: all 256 channels, 4 rowgroups per wave -------
        f32x4 acc[4][4];
#pragma unroll
        for (int rg = 0; rg < 4; rg++)
#pragma unroll
            for (int nt = 0; nt < 4; nt++) acc[rg][nt] = (f32x4)0.0f;

#pragma unroll
        for (int i = 0; i < 3; i++)
            gl_lds16(xhi + gofs[i], SMEM + w*192 + i*64);
        __syncthreads();

        for (int cc = 0; cc < 8; cc++) {
            const int buf = cc & 1;
            const uint4* sH = SMEM + buf*768;
            if (cc < 7) {
                uint4* nB = SMEM + (buf^1)*768;
#pragma unroll
                for (int i = 0; i < 3; i++)
                    gl_lds16(xhi + gofs[i] + (cc+1)*32, nB + w*192 + i*64);
            }
#pragma unroll
            for (int s = 0; s < 9; s++) {
                const int dx = s % 3 - 1;
                const int r = s / 3;
                short8 a[4];
#pragma unroll
                for (int rg = 0; rg < 4; rg++) {
                    const size_t aoff = (((size_t)((4 + w*4 + rg)*9 + s)*8 + cc)*64 + L)*8;
                    a[rg] = *(const short8*)(Ahi + aoff);
                }
#pragma unroll
                for (int nt = 0; nt < 4; nt++) {
                    const int col = nt*16 + ln + dx + 1;
                    const short8 bf = *(const short8*)&sH[SWZ(r, col, quad)];
#pragma unroll
                    for (int rg = 0; rg < 4; rg++)
                        acc[rg][nt] = MFMA16(a[rg], bf, acc[rg][nt]);
                }
            }
            __syncthreads();
        }

        // ---- epilogue: LDS transpose (256ch x 56px) -> dense Vf tiles ----
        unsigned short* Vs = (unsigned short*)SMEM;   // [256][VSTR]
#pragma unroll
        for (int rg = 0; rg < 4; rg++)
#pragma unroll
            for (int nt = 0; nt < 4; nt++) {
                const int px = nt*16 + ln;
                if (px >= 56) continue;
#pragma unroll
                for (int r = 0; r < 4; r++) {
                    const int cl = (w*4 + rg)*16 + quad*4 + r;
                    Vs[cl*VSTR + px] = f2bf(acc[rg][nt][r] + bv[cl]);
                }
            }
        __syncthreads();
        const int p0 = y*56;
        const int hh = L >> 5, c31 = L & 31;
        const int gend = (p0 + 55) >> 4;
        for (int gi = p0 >> 4; gi <= gend; gi++) {
            const int pxl0 = gi*16 + hh*8 - p0;
            if (pxl0 >= 0 && pxl0 + 8 <= 56) {
#pragma unroll
                for (int cgk = 0; cgk < 2; cgk++) {
                    const int cg = w*2 + cgk;
                    const short8 vv = *(const short8*)&Vs[(cg*32 + c31)*VSTR + pxl0];
                    const size_t o = ((((size_t)(b*8 + cg)*49 + (gi >> 2))*4 + (gi & 3))*64 + L)*8;
                    *(short8*)(vbf + o) = vv;
                }
            }
        }
    }
}

// ---------------------------------------------------------------------------
// Kernel 3: fused flash attention, R9: R7's 2-wave structure (chalf split
// KEPT — R8 proved de-duplicating S onto a barrier-serialized path loses),
// jh split REMOVED: each block walks all 49 j-tiles, owns the full (m,l)
// for its rows, and FINALIZES in-kernel: out = x + (gamma/l)*O.
// Kills the partial-O round trip, coef_pre, and combine (~103MB traffic).
// grid (98*8, chalf 2) = 1568 blocks, block 128 = 2 waves.
// ---------------------------------------------------------------------------
__global__ __launch_bounds__(128, 4) void attn_flash2w(
    const unsigned short* __restrict__ qkt_hi, const unsigned short* __restrict__ qkt_lo,
    const unsigned short* __restrict__ vbf,
    const float* __restrict__ x, const float* __restrict__ gptr,
    float* __restrict__ out)
{
    __shared__ unsigned short P[2][32*PSTR];   // 9.5 KB
    __shared__ float alphaL[2][32];
    __shared__ float lL[32];

    const int bx = blockIdx.x;
    const int b = bx & 7, it = bx >> 3;
    const int chalf = blockIdx.y;
    const int i_base = it * 32;
    const int t = threadIdx.x;
    const int w = t >> 6, L = t & 63;
    const int ln = L & 15, quad = L >> 4;
    const int l32 = L & 31, h32 = L >> 5;

    const unsigned short* Kf_hi = qkt_hi + QF_ELEMS;
    const unsigned short* Kf_lo = qkt_lo + QF_ELEMS;

    const size_t qoff = ((size_t)(b*196 + it*2 + w)*64 + L)*8;
    const short8 qh = *(const short8*)(qkt_hi + qoff);
    const short8 ql = *(const short8*)(qkt_lo + qoff);

    float m_run = -INFINITY, l_run = 0.0f;
    f32x16 O0 = (f32x16)0.0f, O1 = (f32x16)0.0f;
    const int cg0 = chalf*4 + w*2;
    const unsigned short* vt0 = vbf + ((size_t)(b*8 + cg0)*49)*2048 + (size_t)L*8;
    const unsigned short* vt1 = vt0 + (size_t)49*2048;
    const unsigned short* kbh = Kf_hi + (size_t)b*49*2048 + (size_t)L*8;
    const unsigned short* kbl = Kf_lo + (size_t)b*49*2048 + (size_t)L*8;

    for (int jt = 0; jt < 49; jt++) {
        const int buf = jt & 1;

        // ---- V prefetch (hidden under S-phase) ----
        short8 Va[4], Vb[4];
#pragma unroll
        for (int s = 0; s < 4; s++) {
            Va[s] = *(const short8*)(vt0 + jt*2048 + s*512);
            Vb[s] = *(const short8*)(vt1 + jt*2048 + s*512);
        }

        // ---- S^T phase ----
        f32x4 sacc[4];
#pragma unroll
        for (int tj = 0; tj < 4; tj++) {
            const short8 kh = *(const short8*)(kbh + jt*2048 + tj*512);
            const short8 kl = *(const short8*)(kbl + jt*2048 + tj*512);
            f32x4 a = (f32x4)0.0f;
            a = MFMA16(kh, qh, a);
            a = MFMA16(kh, ql, a);
            a = MFMA16(kl, qh, a);
            sacc[tj] = a;
        }
        float mt0 = fmaxf(fmaxf(sacc[0][0], sacc[0][1]), fmaxf(sacc[0][2], sacc[0][3]));
        float mt1 = fmaxf(fmaxf(sacc[1][0], sacc[1][1]), fmaxf(sacc[1][2], sacc[1][3]));
        float mt2 = fmaxf(fmaxf(sacc[2][0], sacc[2][1]), fmaxf(sacc[2][2], sacc[2][3]));
        float mt3 = fmaxf(fmaxf(sacc[3][0], sacc[3][1]), fmaxf(sacc[3][2], sacc[3][3]));
        float mx = fmaxf(fmaxf(mt0, mt1), fmaxf(mt2, mt3));
        mx = fmaxf(mx, __shfl_xor(mx, 16));
        mx = fmaxf(mx, __shfl_xor(mx, 32));

        float alpha = 1.0f;
        if (__any(mx > m_run + 8.0f)) {      // defer-max (T13), exp2 domain
            const float m_new = fmaxf(m_run, mx);
            alpha = exp2_hw(m_run - m_new);
            m_run = m_new;
        }

#pragma unroll
        for (int tj = 0; tj < 4; tj++)
#pragma unroll
            for (int r = 0; r < 4; r++)
                sacc[tj][r] = exp2_hw(sacc[tj][r] - m_run);
        float s0 = (sacc[0][0] + sacc[0][1]) + (sacc[0][2] + sacc[0][3]);
        float s1 = (sacc[1][0] + sacc[1][1]) + (sacc[1][2] + sacc[1][3]);
        float s2 = (sacc[2][0] + sacc[2][1]) + (sacc[2][2] + sacc[2][3]);
        float s3 = (sacc[3][0] + sacc[3][1]) + (sacc[3][2] + sacc[3][3]);
        float ps = (s0 + s1) + (s2 + s3);
        ps += __shfl_xor(ps, 16);
        ps += __shfl_xor(ps, 32);
        l_run = l_run * alpha + ps;

        {
            unsigned short* prow = &P[buf][(w*16 + ln)*PSTR];
#pragma unroll
            for (int tj = 0; tj < 4; tj++) {
                uint2 pp;
                pp.x = cvt_pk_bf16(sacc[tj][0], sacc[tj][1]);
                pp.y = cvt_pk_bf16(sacc[tj][2], sacc[tj][3]);
                *(uint2*)(prow + tj*16 + quad*4) = pp;
            }
        }
        if (quad == 0) alphaL[buf][w*16 + ln] = alpha;

        __syncthreads();   // P[buf] + alphaL[buf] ready

        // ---- PV phase ----
        const float a = alphaL[buf][l32];
        if (__any(a != 1.0f)) {
#pragma unroll
            for (int rg = 0; rg < 16; rg++) { O0[rg] *= a; O1[rg] *= a; }
        }
        short8 Bp[4];
#pragma unroll
        for (int s = 0; s < 4; s++) {
            Bp[s] = *(const short8*)&P[buf][l32*PSTR + s*16 + h32*8];
            O0 = MFMA32(Va[s], Bp[s], O0);
        }
#pragma unroll
        for (int s = 0; s < 4; s++)
            O1 = MFMA32(Vb[s], Bp[s], O1);
    }

    // ---- epilogue: finalize in-kernel (no partials, no combine) ----
    __syncthreads();                 // all PV reads of alphaL done
    if (quad == 0) lL[w*16 + ln] = l_run;
    __syncthreads();
    const float inv = gptr[0] / lL[l32];

    const int pix = i_base + l32;
#pragma unroll
    for (int g = 0; g < 2; g++) {
        const f32x16 Ot = g ? O1 : O0;
        const int cg = chalf*128 + w*64 + g*32;
#pragma unroll
        for (int reg = 0; reg < 16; reg++) {
            const int c = cg + (reg & 3) + 8*(reg >> 2) + 4*h32;
            const size_t idx = (size_t)(b*C_ + c)*N_ + pix;
            out[idx] = x[idx] + inv * Ot[reg];
        }
    }
}

// ---------------------------------------------------------------------------
extern "C" void kernel_launch(void* const* d_in, const int* in_sizes, int n_in,
                              void* d_out, int out_size, void* d_ws, size_t ws_size,
                              hipStream_t stream)
{
    (void)in_sizes; (void)n_in; (void)out_size; (void)ws_size;
    const float* x  = (const float*)d_in[0];
    const float* wq = (const float*)d_in[1];
    const float* bq = (const float*)d_in[2];
    const float* wk = (const float*)d_in[3];
    const float* bk = (const float*)d_in[4];
    const float* wv = (const float*)d_in[5];
    const float* bv = (const float*)d_in[6];
    const float* gm = (const float*)d_in[7];
    float* out = (float*)d_out;

    unsigned short* u = (unsigned short*)d_ws;
    unsigned short* xhi = u;                      // conv input
    unsigned short* xlo = u + XT_ELEMS;           // conv input
    unsigned short* Ahi = u + AHI_OFF;            // Af weights
    unsigned short* Alo = u + ALO_OFF;
    unsigned short* qkt_hi = u + QKT_HI_OFF;      // [Qf_hi | Kf_hi]
    unsigned short* qkt_lo = u + QKT_LO_OFF;      // [Qf_lo | Kf_lo]
    unsigned short* vbf = u + VBF_OFF;            // Vf fragment-order

    hipLaunchKernelGGL(zero_pads, dim3(480), dim3(256), 0, stream, xhi, xlo);
    hipLaunchKernelGGL(prep_x, dim3(4, 56, 8), dim3(256), 0, stream, x, xhi, xlo);
    hipLaunchKernelGGL(prep_w, dim3(2880), dim3(256), 0, stream, wq, wk, wv, Ahi, Alo);
    hipLaunchKernelGGL(conv_fused, dim3(8, 56, 2), dim3(256), 0, stream,
                       xhi, xlo, Ahi, Alo, bq, bk, bv, qkt_hi, qkt_lo, vbf);
    hipLaunchKernelGGL(attn_flash2w, dim3(98*8, 2), dim3(128), 0, stream,
                       qkt_hi, qkt_lo, vbf, x, gm, out);
}